// Round 3
// baseline (3974.357 us; speedup 1.0000x reference)
//
#include <hip/hip_runtime.h>
#include <stdint.h>

#define NSZ 2048
#define NLAYERS 4

typedef __attribute__((ext_vector_type(4))) float f32x4;

// ---------------- CSR build ----------------
__global__ void k_zero(int* __restrict__ p, int n) {
  int i = blockIdx.x * 256 + threadIdx.x;
  if (i < n) p[i] = 0;
}

__global__ void k_count(const int* __restrict__ tgt, int E, int* __restrict__ cnt) {
  int e = blockIdx.x * 256 + threadIdx.x;
  if (e < E) atomicAdd(&cnt[tgt[e] & (NSZ - 1)], 1);
}

__global__ __launch_bounds__(1024) void k_scan(
    const int* __restrict__ cntA, int* __restrict__ offA, int* __restrict__ curA,
    float* __restrict__ invA, int EA,
    const int* __restrict__ cntB, int* __restrict__ offB, int* __restrict__ curB,
    float* __restrict__ invB, int EB) {
  const int* cnt; int* off; int* cur; float* inv; int E;
  if (blockIdx.x == 0) { cnt = cntA; off = offA; cur = curA; inv = invA; E = EA; }
  else                 { cnt = cntB; off = offB; cur = curB; inv = invB; E = EB; }
  __shared__ int sa[2048], sb[2048];
  int t = threadIdx.x;
  sa[t] = cnt[t]; sa[t + 1024] = cnt[t + 1024];
  __syncthreads();
  int* s = sa; int* d = sb;
  for (int dd = 1; dd < 2048; dd <<= 1) {
    for (int i = t; i < 2048; i += 1024)
      d[i] = s[i] + ((i >= dd) ? s[i - dd] : 0);
    __syncthreads();
    int* tmp = s; s = d; d = tmp;
  }
  for (int i = t; i < 2048; i += 1024) {
    int o = (i == 0) ? 0 : s[i - 1];
    off[i] = o; cur[i] = o;
    int c = cnt[i];
    inv[i] = 1.0f / (float)((c > 1) ? c : 1);
  }
  if (t == 0) off[2048] = E;
}

__global__ void k_fill(const int* __restrict__ src, const int* __restrict__ tgt, int E,
                       int* __restrict__ cur, int* __restrict__ srcs) {
  int e = blockIdx.x * 256 + threadIdx.x;
  if (e < E) {
    int p = atomicAdd(&cur[tgt[e] & (NSZ - 1)], 1);
    if (p >= 0 && p < E) srcs[p] = src[e] & (NSZ - 1);
  }
}

// ---------------- fp32 2048x2048 transpose: d = s^T ----------------
__global__ __launch_bounds__(256) void k_transpose(const float* __restrict__ s,
                                                   float* __restrict__ d) {
  __shared__ float tile[64][65];
  const int tid = threadIdx.x;
  const int r0 = blockIdx.y << 6, c0 = blockIdx.x << 6;
#pragma unroll
  for (int it = 0; it < 4; ++it) {
    int e = it * 256 + tid;
    int r = e >> 4;
    int c = (e & 15) << 2;
    f32x4 v = *(const f32x4*)&s[(size_t)(r0 + r) * NSZ + c0 + c];
#pragma unroll
    for (int j = 0; j < 4; ++j) tile[r][c + j] = v[j];
  }
  __syncthreads();
#pragma unroll
  for (int it = 0; it < 4; ++it) {
    int e = it * 256 + tid;
    int r = e >> 4;          // output row within tile (input col)
    int c = (e & 15) << 2;   // output col chunk (input row)
    f32x4 v;
#pragma unroll
    for (int j = 0; j < 4; ++j) v[j] = tile[c + j][r];
    *(f32x4*)&d[(size_t)(c0 + r) * NSZ + r0 + c] = v;
  }
}

// ---------------- fp32 NN GEMM: C[m,n] = sum_k A[m,k]*B[k,n] ----------------
// M=2048, K=2048, N=4096 where B is [Bl | Br], each [2048,2048] row-major.
// BM=BN=128, BK=16, 256 threads, 8x8 per thread.
#define APAD 132
__global__ __launch_bounds__(256) void k_gemm(const float* __restrict__ A,
                                              const float* __restrict__ Bl,
                                              const float* __restrict__ Br,
                                              float* __restrict__ C) {
  __shared__ float Ast[16][APAD];   // [k][m] transposed
  __shared__ float Bs[16][128];     // [k][n]
  const int tid = threadIdx.x;
  const int bm = blockIdx.x & 15;          // 16 M-tiles
  const int bn = blockIdx.x >> 4;          // 32 N-tiles
  const int m0 = bm << 7;
  const int n0 = bn << 7;
  const float* Bmat = (n0 < NSZ) ? Bl : Br;
  const int nb0 = n0 & (NSZ - 1);

  const int tm = tid & 15;                 // 0..15 -> rows tm*8..+8
  const int tn = tid >> 4;                 // 0..15 -> cols tn*8..+8

  float acc[8][8];
#pragma unroll
  for (int i = 0; i < 8; ++i)
#pragma unroll
    for (int j = 0; j < 8; ++j) acc[i][j] = 0.f;

  for (int k0 = 0; k0 < NSZ; k0 += 16) {
    // stage A-tile: 128 rows x 16 k = 512 float4
#pragma unroll
    for (int it = 0; it < 2; ++it) {
      int f = it * 256 + tid;
      int r = f >> 2;
      int c4 = (f & 3) << 2;
      f32x4 v = *(const f32x4*)&A[(size_t)(m0 + r) * NSZ + k0 + c4];
#pragma unroll
      for (int j = 0; j < 4; ++j) Ast[c4 + j][r] = v[j];
    }
    // stage B-tile: 16 k x 128 n = 512 float4
#pragma unroll
    for (int it = 0; it < 2; ++it) {
      int f = it * 256 + tid;
      int k = f >> 5;
      int n4 = (f & 31) << 2;
      f32x4 v = *(const f32x4*)&Bmat[(size_t)(k0 + k) * NSZ + nb0 + n4];
      *(f32x4*)&Bs[k][n4] = v;
    }
    __syncthreads();
#pragma unroll
    for (int kk = 0; kk < 16; ++kk) {
      float af[8], bf[8];
#pragma unroll
      for (int j = 0; j < 4; ++j) af[j] = Ast[kk][tm * 8 + j];
#pragma unroll
      for (int j = 0; j < 4; ++j) af[4 + j] = Ast[kk][tm * 8 + 4 + j];
      f32x4 b0 = *(const f32x4*)&Bs[kk][tn * 8];
      f32x4 b1 = *(const f32x4*)&Bs[kk][tn * 8 + 4];
#pragma unroll
      for (int j = 0; j < 4; ++j) { bf[j] = b0[j]; bf[4 + j] = b1[j]; }
#pragma unroll
      for (int i = 0; i < 8; ++i)
#pragma unroll
        for (int j = 0; j < 8; ++j)
          acc[i][j] = __builtin_fmaf(af[i], bf[j], acc[i][j]);
    }
    __syncthreads();
  }

#pragma unroll
  for (int i = 0; i < 8; ++i) {
    f32x4 v0, v1;
#pragma unroll
    for (int j = 0; j < 4; ++j) { v0[j] = acc[i][j]; v1[j] = acc[i][4 + j]; }
    float* Crow = &C[(size_t)(m0 + tm * 8 + i) * 4096 + n0 + tn * 8];
    *(f32x4*)&Crow[0] = v0;
    *(f32x4*)&Crow[4] = v1;
  }
}

// ---------------- fused mean-gather + self + bias + LeakyReLU (+optional transpose) ----------------
// Cb: [2048 x 4096] fp32; cols [0,2048) = X@Wl, [2048,4096) = X@Wr.
// transpose_out=1: out[feature*2048 + target]; else out[target*2048 + feature].
__global__ __launch_bounds__(256) void k_fuse(const float* __restrict__ Cb,
                                              const int* __restrict__ off,
                                              const int* __restrict__ srcs,
                                              const float* __restrict__ inv,
                                              const float* __restrict__ bias,
                                              float* __restrict__ out,
                                              int transpose_out, int E) {
  __shared__ float tile[64][65];
  const int tid = threadIdx.x;
  const int w = tid >> 6;
  const int lane = tid & 63;
  const int t0 = blockIdx.y << 6;   // targets
  const int f0 = blockIdx.x << 6;   // features
  const int fc = f0 + lane;
  const float b = bias[fc];

  for (int it = 0; it < 16; ++it) {
    int lt = (w << 4) + it;
    int c = t0 + lt;
    int e0 = off[c], e1 = off[c + 1];
    if (e1 > E) e1 = E;
    if (e0 < 0) e0 = 0;
    float acc = 0.f;
    int e = e0;
    while (e + 8 <= e1) {
      float p[8];
#pragma unroll
      for (int q = 0; q < 8; ++q)
        p[q] = Cb[(size_t)(srcs[e + q] & (NSZ - 1)) * 4096 + fc];
#pragma unroll
      for (int q = 0; q < 8; ++q) acc += p[q];
      e += 8;
    }
    while (e < e1) { acc += Cb[(size_t)(srcs[e] & (NSZ - 1)) * 4096 + fc]; ++e; }
    float val = acc * inv[c] + Cb[(size_t)c * 4096 + 2048 + fc] + b;
    val = (val > 0.f) ? val : 0.01f * val;
    tile[lt][lane] = val;
  }
  __syncthreads();
  for (int it = 0; it < 4; ++it) {
    int f = it * 256 + tid;
    int r = f >> 4;
    int c4 = (f & 15) << 2;
    f32x4 v;
    if (transpose_out) {
#pragma unroll
      for (int j = 0; j < 4; ++j) v[j] = tile[c4 + j][r];
      *(f32x4*)&out[(size_t)(f0 + r) * NSZ + t0 + c4] = v;
    } else {
#pragma unroll
      for (int j = 0; j < 4; ++j) v[j] = tile[r][c4 + j];
      *(f32x4*)&out[(size_t)(t0 + r) * NSZ + f0 + c4] = v;
    }
  }
}

extern "C" void kernel_launch(void* const* d_in, const int* in_sizes, int n_in,
                              void* d_out, int out_size, void* d_ws, size_t ws_size,
                              hipStream_t stream) {
  (void)n_in; (void)out_size; (void)ws_size;
  const float* x      = (const float*)d_in[0];
  const int*   knn    = (const int*)d_in[1];
  const int*   ppi    = (const int*)d_in[2];
  const float* col_Wl = (const float*)d_in[3];
  const float* col_bl = (const float*)d_in[4];
  const float* col_Wr = (const float*)d_in[5];
  const float* row_Wl = (const float*)d_in[6];
  const float* row_bl = (const float*)d_in[7];
  const float* row_Wr = (const float*)d_in[8];
  float* out = (float*)d_out;
  const int E_knn = in_sizes[1] / 2;
  const int E_ppi = in_sizes[2] / 2;
  const size_t NN = (size_t)NSZ * NSZ;

  // ---- workspace layout: small CSR arrays first, then fp32 Cbuf (~33 MB total) ----
  char* ws = (char*)d_ws;
  size_t off_b = 0;
  int*   cnt_knn = (int*)(ws + off_b);   off_b += 2048 * 4;
  int*   cnt_ppi = (int*)(ws + off_b);   off_b += 2048 * 4;
  int*   off_knn = (int*)(ws + off_b);   off_b += 2064 * 4;
  int*   off_ppi = (int*)(ws + off_b);   off_b += 2064 * 4;
  int*   cur_knn = (int*)(ws + off_b);   off_b += 2048 * 4;
  int*   cur_ppi = (int*)(ws + off_b);   off_b += 2048 * 4;
  float* inv_knn = (float*)(ws + off_b); off_b += 2048 * 4;
  float* inv_ppi = (float*)(ws + off_b); off_b += 2048 * 4;
  int*   src_knn = (int*)(ws + off_b);   off_b += (size_t)((E_knn + 63) & ~63) * 4;
  int*   src_ppi = (int*)(ws + off_b);   off_b += (size_t)((E_ppi + 63) & ~63) * 4;
  off_b = (off_b + 255) & ~(size_t)255;
  float* Cbuf = (float*)(ws + off_b); off_b += NN * 2 * 4;   // [2048 x 4096] fp32 = 32 MB
  float* state = out;                                        // d_out doubles as state (16 MB fp32)

  // ---- CSR build for both graphs ----
  k_zero<<<16, 256, 0, stream>>>(cnt_knn, 4096);  // cnt_knn & cnt_ppi adjacent
  k_count<<<(E_knn + 255) / 256, 256, 0, stream>>>(knn + E_knn, E_knn, cnt_knn);
  k_count<<<(E_ppi + 255) / 256, 256, 0, stream>>>(ppi + E_ppi, E_ppi, cnt_ppi);
  k_scan<<<2, 1024, 0, stream>>>(cnt_knn, off_knn, cur_knn, inv_knn, E_knn,
                                 cnt_ppi, off_ppi, cur_ppi, inv_ppi, E_ppi);
  k_fill<<<(E_knn + 255) / 256, 256, 0, stream>>>(knn, knn + E_knn, E_knn, cur_knn, src_knn);
  k_fill<<<(E_ppi + 255) / 256, 256, 0, stream>>>(ppi, ppi + E_ppi, E_ppi, cur_ppi, src_ppi);

  // ---- state = x^T  [cells, genes] ----
  {
    dim3 g(32, 32);
    k_transpose<<<g, 256, 0, stream>>>(x, state);
  }

  for (int i = 0; i < NLAYERS; ++i) {
    dim3 gf(32, 32);
    // cols side: C[cell, 0:2048] = h^T@col_Wl ; C[cell, 2048:4096] = h^T@col_Wr  (NN GEMM)
    k_gemm<<<512, 256, 0, stream>>>(state, col_Wl + (size_t)i * NN, col_Wr + (size_t)i * NN, Cbuf);
    // h_mid[gene, cell] = leaky(mean_knn + self + bl)   (transposed write)
    k_fuse<<<gf, 256, 0, stream>>>(Cbuf, off_knn, src_knn, inv_knn,
                                   col_bl + (size_t)i * NSZ, state, 1, E_knn);
    // rows side
    k_gemm<<<512, 256, 0, stream>>>(state, row_Wl + (size_t)i * NN, row_Wr + (size_t)i * NN, Cbuf);
    // layers 0-2: write h^T [cell, gene]; layer 3: write h [gene, cell] to d_out
    k_fuse<<<gf, 256, 0, stream>>>(Cbuf, off_ppi, src_ppi, inv_ppi,
                                   row_bl + (size_t)i * NSZ, out,
                                   (i < NLAYERS - 1) ? 1 : 0, E_ppi);
  }
}